// Round 2
// baseline (689.127 us; speedup 1.0000x reference)
//
#include <hip/hip_runtime.h>
#include <cstdint>

// IFS fractal step (all float32):
//   tp = selu(points @ M[choice] + b[choice])        -> out[0 .. N*3)
//   new_colors = (prev_colors + colors[choice]) * 0.5 -> out[N*3 .. 2*N*3)
// Memory-bound: 28 B read + 24 B write per point = 872 MB total, floor ~140 us @ 6.3 TB/s.

__device__ __forceinline__ float selu_f(float x) {
    const float alpha = 1.6732632423543772f;
    const float scale = 1.0507009873554805f;
    float neg = alpha * (__expf(x) - 1.0f);   // only used for x <= 0 (expf exact enough there)
    return scale * (x > 0.0f ? x : neg);
}

__global__ __launch_bounds__(256) void ifs_kernel(
    const float* __restrict__ points,       // [N,3]
    const float* __restrict__ prev_colors,  // [N,3]
    const int*   __restrict__ choices,      // [N]
    const float* __restrict__ matrices,     // [K,3,3] k*9 + d*3 + e
    const float* __restrict__ biases,       // [K,3]
    const float* __restrict__ colors,       // [K,3]
    float* __restrict__ out_tp,             // [N,3]
    float* __restrict__ out_col,            // [N,3]
    long long n_points)
{
    // LDS transform table, stride 17 floats: (17k + j) % 32 distinct for all k in [0,8)
    __shared__ float T[8][17];
    int tid = threadIdx.x;
    if (tid < 8 * 16) {
        int k = tid >> 4, j = tid & 15;
        float v = 0.0f;
        if (j < 9)       v = matrices[k * 9 + j];
        else if (j < 12) v = biases[k * 3 + (j - 9)];
        else if (j < 15) v = colors[k * 3 + (j - 12)];
        T[k][j] = v;
    }
    __syncthreads();

    long long g = (long long)blockIdx.x * blockDim.x + tid;
    long long base = g * 4;  // 4 points per thread
    if (base >= n_points) return;

    if (base + 4 <= n_points) {
        // points/prev_colors: 12 floats = 3x float4; choices: 1x int4
        float4 pv[3], cv[3];
        const float4* pp = reinterpret_cast<const float4*>(points + base * 3);
        const float4* pc = reinterpret_cast<const float4*>(prev_colors + base * 3);
        const int4*   cc = reinterpret_cast<const int4*>(choices + base);
        pv[0] = pp[0]; pv[1] = pp[1]; pv[2] = pp[2];
        cv[0] = pc[0]; cv[1] = pc[1]; cv[2] = pc[2];
        int4 ch = cc[0];

        const float* pb = reinterpret_cast<const float*>(pv);
        const float* cb = reinterpret_cast<const float*>(cv);
        const int*   ci = reinterpret_cast<const int*>(&ch);

        float4 ov[3], oc[3];
        float* ob  = reinterpret_cast<float*>(ov);
        float* ocb = reinterpret_cast<float*>(oc);

        #pragma unroll
        for (int j = 0; j < 4; ++j) {
            int k = ci[j] & 7;
            const float* t = T[k];
            float x = pb[3 * j + 0];
            float y = pb[3 * j + 1];
            float z = pb[3 * j + 2];
            // tp[e] = sum_d p[d] * M[d*3+e] + b[e]   (contract over FIRST axis of M)
            float e0 = fmaf(x, t[0], fmaf(y, t[3], fmaf(z, t[6], t[9])));
            float e1 = fmaf(x, t[1], fmaf(y, t[4], fmaf(z, t[7], t[10])));
            float e2 = fmaf(x, t[2], fmaf(y, t[5], fmaf(z, t[8], t[11])));
            ob[3 * j + 0] = selu_f(e0);
            ob[3 * j + 1] = selu_f(e1);
            ob[3 * j + 2] = selu_f(e2);
            ocb[3 * j + 0] = (cb[3 * j + 0] + t[12]) * 0.5f;
            ocb[3 * j + 1] = (cb[3 * j + 1] + t[13]) * 0.5f;
            ocb[3 * j + 2] = (cb[3 * j + 2] + t[14]) * 0.5f;
        }

        float4* ot = reinterpret_cast<float4*>(out_tp + base * 3);
        float4* oo = reinterpret_cast<float4*>(out_col + base * 3);
        ot[0] = ov[0]; ot[1] = ov[1]; ot[2] = ov[2];
        oo[0] = oc[0]; oo[1] = oc[1]; oo[2] = oc[2];
    } else {
        // scalar tail
        for (long long p = base; p < n_points; ++p) {
            int k = choices[p] & 7;
            const float* t = T[k];
            float x = points[p * 3 + 0];
            float y = points[p * 3 + 1];
            float z = points[p * 3 + 2];
            float e0 = fmaf(x, t[0], fmaf(y, t[3], fmaf(z, t[6], t[9])));
            float e1 = fmaf(x, t[1], fmaf(y, t[4], fmaf(z, t[7], t[10])));
            float e2 = fmaf(x, t[2], fmaf(y, t[5], fmaf(z, t[8], t[11])));
            out_tp[p * 3 + 0] = selu_f(e0);
            out_tp[p * 3 + 1] = selu_f(e1);
            out_tp[p * 3 + 2] = selu_f(e2);
            out_col[p * 3 + 0] = (prev_colors[p * 3 + 0] + t[12]) * 0.5f;
            out_col[p * 3 + 1] = (prev_colors[p * 3 + 1] + t[13]) * 0.5f;
            out_col[p * 3 + 2] = (prev_colors[p * 3 + 2] + t[14]) * 0.5f;
        }
    }
}

extern "C" void kernel_launch(void* const* d_in, const int* in_sizes, int n_in,
                              void* d_out, int out_size, void* d_ws, size_t ws_size,
                              hipStream_t stream) {
    const float* points      = (const float*)d_in[0];
    const float* prev_colors = (const float*)d_in[1];
    const int*   choices     = (const int*)d_in[2];
    const float* matrices    = (const float*)d_in[3];
    const float* biases      = (const float*)d_in[4];
    const float* colors      = (const float*)d_in[5];

    long long n = in_sizes[2];  // choices: one per point
    float* out_tp  = (float*)d_out;
    float* out_col = out_tp + (size_t)n * 3;

    long long n_threads = (n + 3) / 4;
    int block = 256;
    long long grid = (n_threads + block - 1) / block;
    ifs_kernel<<<(dim3)(unsigned int)grid, block, 0, stream>>>(
        points, prev_colors, choices, matrices, biases, colors,
        out_tp, out_col, n);
}